// Round 2
// baseline (425.191 us; speedup 1.0000x reference)
//
#include <hip/hip_runtime.h>

#define DEVINL __device__ __forceinline__

// Problem constants
#define BB 4
#define SS 4096
#define HIDD 1024
#define HH 16
#define DH 64
#define NQKV 3072
#define MM (BB * SS)  // 16384

typedef __attribute__((ext_vector_type(8))) short bf16x8_t;
typedef __attribute__((ext_vector_type(4))) float f32x4_t;

typedef __attribute__((address_space(1))) const void GV;
typedef __attribute__((address_space(3))) void LV;

DEVINL void gload16(const void* g, void* l) {
  // async global->LDS, 16B/lane; LDS dest = wave-uniform base + lane*16
  __builtin_amdgcn_global_load_lds((GV*)g, (LV*)l, 16, 0, 0);
}

DEVINL float bf2f(ushort u) {
  union { unsigned int i; float f; } v;
  v.i = ((unsigned int)u) << 16;
  return v.f;
}
DEVINL ushort f2bf(float f) {
  unsigned int u = __float_as_uint(f);
  u = (u + 0x7fffu + ((u >> 16) & 1u)) >> 16;
  return (ushort)u;
}

// ---------------- fp32 -> bf16 convert (4 elems/thread) ----------------
__global__ __launch_bounds__(256) void k_f2bf(const float* __restrict__ src,
                                              ushort* __restrict__ dst, int n4) {
  int i = blockIdx.x * 256 + threadIdx.x;
  if (i >= n4) return;
  float4 v = ((const float4*)src)[i];
  ushort4 o;
  o.x = f2bf(v.x); o.y = f2bf(v.y); o.z = f2bf(v.z); o.w = f2bf(v.w);
  ((ushort4*)dst)[i] = o;
}

// ---------------- bf16 GEMM: C[M,N] = A[M,K] * B[N,K]^T + bias ----------------
// 128x128 tile, BK=64, 4 waves (2x2), each wave 4x4 frags of 16x16x32 MFMA.
// Staging: global_load_lds width=16, LINEAR LDS dest + pre-swizzled global
// source (chunk ^= row&7); reads use the same swizzle (rule #21).
// XCD-aware bijective block swizzle (T1); requires nwg % 8 == 0.
template <int STORE_F32>
__global__ __launch_bounds__(256) void k_gemm_bt(
    const ushort* __restrict__ A, const ushort* __restrict__ B,
    const float* __restrict__ bias, void* __restrict__ Cv,
    int M, int N, int K) {
  __shared__ ushort As[128 * 64];
  __shared__ ushort Bs[128 * 64];
  const int t = threadIdx.x;

  // XCD swizzle: XCD k gets a contiguous chunk of logical tiles, M-fast.
  int wg = blockIdx.x + blockIdx.y * gridDim.x;
  int nwg = gridDim.x * gridDim.y;
  int qq = nwg >> 3;
  int wg2 = (wg & 7) * qq + (wg >> 3);
  int mt = wg2 & (gridDim.x - 1);   // gridDim.x is a power of 2 (128)
  int ntile = wg2 / gridDim.x;
  const int m0 = mt * 128, n0 = ntile * 128;

  const int lane = t & 63, wave = t >> 6;
  const int wm = wave >> 1, wn = wave & 1;
  const int fr = lane & 15, g = lane >> 4;

  // staging lane constants: lane covers (row-group rg)*8 + rsub, 16B chunk l&7
  const int rsub = lane >> 3;                 // 0..7 row within group
  const int gcol = ((lane & 7) ^ rsub) * 8;   // pre-swizzled global chunk (ushorts)

  f32x4_t acc[4][4] = {};
  for (int k0 = 0; k0 < K; k0 += 64) {
#pragma unroll
    for (int i = 0; i < 4; ++i) {
      int rg = wave * 4 + i;                  // row-group 0..15 (8 rows = 1KB each)
      int row = rg * 8 + rsub;
      gload16(&A[(size_t)(m0 + row) * K + k0 + gcol], &As[rg * 512]);
      gload16(&B[(size_t)(n0 + row) * K + k0 + gcol], &Bs[rg * 512]);
    }
    __syncthreads();
#pragma unroll
    for (int kk = 0; kk < 2; ++kk) {
      bf16x8_t af[4], bfg[4];
#pragma unroll
      for (int mi = 0; mi < 4; ++mi) {
        int r = wm * 64 + mi * 16 + fr;
        af[mi] = *(const bf16x8_t*)&As[r * 64 + (((kk * 4 + g) ^ (r & 7)) * 8)];
      }
#pragma unroll
      for (int ni = 0; ni < 4; ++ni) {
        int r = wn * 64 + ni * 16 + fr;
        bfg[ni] = *(const bf16x8_t*)&Bs[r * 64 + (((kk * 4 + g) ^ (r & 7)) * 8)];
      }
#pragma unroll
      for (int mi = 0; mi < 4; ++mi)
#pragma unroll
        for (int ni = 0; ni < 4; ++ni)
          acc[mi][ni] = __builtin_amdgcn_mfma_f32_16x16x32_bf16(
              af[mi], bfg[ni], acc[mi][ni], 0, 0, 0);
    }
    __syncthreads();
  }
// epilogue: D col = lane&15, row = (lane>>4)*4 + reg (HW-verified mapping)
#pragma unroll
  for (int ni = 0; ni < 4; ++ni) {
    int col = n0 + wn * 64 + ni * 16 + fr;
    float bv = bias[col];
#pragma unroll
    for (int mi = 0; mi < 4; ++mi) {
      int row = m0 + wm * 64 + mi * 16 + g * 4;
#pragma unroll
      for (int j = 0; j < 4; ++j) {
        float v = acc[mi][ni][j] + bv;
        if (STORE_F32)
          ((float*)Cv)[(size_t)(row + j) * N + col] = v;
        else
          ((ushort*)Cv)[(size_t)(row + j) * N + col] = f2bf(v);
      }
    }
  }
}

// ---------------- norms: partial sum of squares over s (per b,h,d) ----------------
// grid 256: block = bh*4 + part; part covers 1024 s values.
__global__ __launch_bounds__(256) void k_norms_part(const ushort* __restrict__ qkv,
                                                    float* __restrict__ part) {
  int bh = blockIdx.x >> 2, p = blockIdx.x & 3;
  int b = bh >> 4, h = bh & 15;
  int t = threadIdx.x;
  int d = t & 63, sg = t >> 6;
  const ushort* base = qkv + (size_t)(b * SS + p * 1024) * NQKV + h * 64 + d;
  float sq = 0.f, sk = 0.f;
  for (int s = sg; s < 1024; s += 4) {
    float q = bf2f(base[(size_t)s * NQKV]);
    float k = bf2f(base[(size_t)s * NQKV + HIDD]);
    sq += q * q;
    sk += k * k;
  }
  __shared__ float red[512];
  red[t] = sq;
  red[256 + t] = sk;
  __syncthreads();
  if (t < 64) {
    sq = red[t] + red[t + 64] + red[t + 128] + red[t + 192];
    sk = red[256 + t] + red[256 + t + 64] + red[256 + t + 128] + red[256 + t + 192];
    part[((size_t)(bh * 4 + p) * 2 + 0) * 64 + d] = sq;
    part[((size_t)(bh * 4 + p) * 2 + 1) * 64 + d] = sk;
  }
}

__global__ __launch_bounds__(256) void k_norms_fin(const float* __restrict__ part,
                                                   float* __restrict__ invq,
                                                   float* __restrict__ invk) {
  int idx = blockIdx.x * 256 + threadIdx.x;  // 4096 = bh*64 + d
  if (idx >= BB * HH * 64) return;
  int bh = idx >> 6, d = idx & 63;
  float sq = 0.f, sk = 0.f;
#pragma unroll
  for (int p = 0; p < 4; ++p) {
    sq += part[((size_t)(bh * 4 + p) * 2 + 0) * 64 + d];
    sk += part[((size_t)(bh * 4 + p) * 2 + 1) * 64 + d];
  }
  invq[idx] = 1.0f / fmaxf(sqrtf(sq), 1e-12f);
  invk[idx] = 1.0f / fmaxf(sqrtf(sk), 1e-12f);
}

// ---------------- gram partial: Wpart[bh][p][64][64] = sum_{s in part} Q[d,s]K[e,s] ----------------
__global__ __launch_bounds__(256) void k_gram_part(const ushort* __restrict__ qkv,
                                                   float* __restrict__ Wpart) {
  int bh = blockIdx.x, p = blockIdx.y;
  int b = bh >> 4, h = bh & 15;
  __shared__ float Qs[64][68];
  __shared__ float Ks[64][68];
  int t = threadIdx.x;
  int td = t & 15, te = t >> 4;
  float acc[4][4] = {};
  const ushort* qbase = qkv + (size_t)(b * SS + p * 1024) * NQKV + h * 64;
  for (int s0 = 0; s0 < 1024; s0 += 64) {
#pragma unroll
    for (int i = 0; i < 2; ++i) {
      int id = i * 256 + t;  // 512 units of 8 bf16
      int sr = id >> 3, c = id & 7;
      const ushort* ptr = qbase + (size_t)(s0 + sr) * NQKV + c * 8;
      int4 vq = *(const int4*)ptr;
      int4 vk = *(const int4*)(ptr + HIDD);
      const ushort* uq = (const ushort*)&vq;
      const ushort* uk = (const ushort*)&vk;
      float4 qlo = {bf2f(uq[0]), bf2f(uq[1]), bf2f(uq[2]), bf2f(uq[3])};
      float4 qhi = {bf2f(uq[4]), bf2f(uq[5]), bf2f(uq[6]), bf2f(uq[7])};
      float4 klo = {bf2f(uk[0]), bf2f(uk[1]), bf2f(uk[2]), bf2f(uk[3])};
      float4 khi = {bf2f(uk[4]), bf2f(uk[5]), bf2f(uk[6]), bf2f(uk[7])};
      *(float4*)&Qs[sr][c * 8] = qlo;
      *(float4*)&Qs[sr][c * 8 + 4] = qhi;
      *(float4*)&Ks[sr][c * 8] = klo;
      *(float4*)&Ks[sr][c * 8 + 4] = khi;
    }
    __syncthreads();
#pragma unroll 4
    for (int s = 0; s < 64; ++s) {
      float4 q = *(const float4*)&Qs[s][td * 4];
      float4 k = *(const float4*)&Ks[s][te * 4];
      const float qa[4] = {q.x, q.y, q.z, q.w};
      const float ka[4] = {k.x, k.y, k.z, k.w};
#pragma unroll
      for (int i = 0; i < 4; ++i)
#pragma unroll
        for (int j = 0; j < 4; ++j) acc[i][j] += qa[i] * ka[j];
    }
    __syncthreads();
  }
  float* wp = Wpart + (size_t)(bh * 4 + p) * 4096;
#pragma unroll
  for (int i = 0; i < 4; ++i)
#pragma unroll
    for (int j = 0; j < 4; ++j) wp[(td * 4 + i) * 64 + te * 4 + j] = acc[i][j];
}

// ---------------- fused scale + softmax + PV ----------------
__global__ __launch_bounds__(256) void k_pv(const ushort* __restrict__ qkv,
                                            const float* __restrict__ Wpart,
                                            const float* __restrict__ invq,
                                            const float* __restrict__ invk,
                                            const float* __restrict__ temperature,
                                            ushort* __restrict__ attnout) {
  int bh = blockIdx.x, p = blockIdx.y;
  int b = bh >> 4, h = bh & 15;
  __shared__ float attn[64][65];
  __shared__ float Vs[64][68];
  int t = threadIdx.x;
  float tscale = temperature[h] * (1.0f / 32.0f);  // / sqrt(HID)
  for (int idx = t; idx < 4096; idx += 256) {
    int d = idx >> 6, e = idx & 63;
    float s = 0.f;
#pragma unroll
    for (int q = 0; q < 4; ++q) s += Wpart[(size_t)(bh * 4 + q) * 4096 + idx];
    attn[d][e] = s * invq[bh * 64 + d] * invk[bh * 64 + e] * tscale;
  }
  __syncthreads();
  if (t < 64) {
    float m = -1e30f;
#pragma unroll 8
    for (int e = 0; e < 64; ++e) m = fmaxf(m, attn[t][e]);
    float sum = 0.f;
#pragma unroll 8
    for (int e = 0; e < 64; ++e) {
      float v = __expf(attn[t][e] - m);
      attn[t][e] = v;
      sum += v;
    }
    float inv = 1.0f / sum;
#pragma unroll 8
    for (int e = 0; e < 64; ++e) attn[t][e] *= inv;
  }
  __syncthreads();
  int td = t & 15, ts = t >> 4;
  const ushort* vbase = qkv + (size_t)(b * SS + p * 1024) * NQKV + 2 * HIDD + h * 64;
  ushort* obase = attnout + (size_t)(b * SS + p * 1024) * HIDD + h * 64;
  for (int s0 = 0; s0 < 1024; s0 += 64) {
#pragma unroll
    for (int i = 0; i < 2; ++i) {
      int id = i * 256 + t;
      int sr = id >> 3, c = id & 7;
      int4 vv = *(const int4*)(vbase + (size_t)(s0 + sr) * NQKV + c * 8);
      const ushort* uv = (const ushort*)&vv;
      float4 lo = {bf2f(uv[0]), bf2f(uv[1]), bf2f(uv[2]), bf2f(uv[3])};
      float4 hi = {bf2f(uv[4]), bf2f(uv[5]), bf2f(uv[6]), bf2f(uv[7])};
      *(float4*)&Vs[sr][c * 8] = lo;
      *(float4*)&Vs[sr][c * 8 + 4] = hi;
    }
    __syncthreads();
    float acc[4][4] = {};  // [d][s]
#pragma unroll 4
    for (int e = 0; e < 64; ++e) {
      float a0 = attn[td * 4 + 0][e];
      float a1 = attn[td * 4 + 1][e];
      float a2 = attn[td * 4 + 2][e];
      float a3 = attn[td * 4 + 3][e];
      float v0 = Vs[ts * 4 + 0][e];
      float v1 = Vs[ts * 4 + 1][e];
      float v2 = Vs[ts * 4 + 2][e];
      float v3 = Vs[ts * 4 + 3][e];
      acc[0][0] += a0 * v0; acc[0][1] += a0 * v1; acc[0][2] += a0 * v2; acc[0][3] += a0 * v3;
      acc[1][0] += a1 * v0; acc[1][1] += a1 * v1; acc[1][2] += a1 * v2; acc[1][3] += a1 * v3;
      acc[2][0] += a2 * v0; acc[2][1] += a2 * v1; acc[2][2] += a2 * v2; acc[2][3] += a2 * v3;
      acc[3][0] += a3 * v0; acc[3][1] += a3 * v1; acc[3][2] += a3 * v2; acc[3][3] += a3 * v3;
    }
#pragma unroll
    for (int j = 0; j < 4; ++j) {
      ushort4 o;
      o.x = f2bf(acc[0][j]);
      o.y = f2bf(acc[1][j]);
      o.z = f2bf(acc[2][j]);
      o.w = f2bf(acc[3][j]);
      *(ushort4*)&obase[(size_t)(s0 + ts * 4 + j) * HIDD + td * 4] = o;
    }
    __syncthreads();
  }
}

extern "C" void kernel_launch(void* const* d_in, const int* in_sizes, int n_in,
                              void* d_out, int out_size, void* d_ws, size_t ws_size,
                              hipStream_t stream) {
  const float* x = (const float*)d_in[0];
  const float* Wqkv = (const float*)d_in[1];
  const float* bqkv = (const float*)d_in[2];
  const float* Wz = (const float*)d_in[3];
  const float* bz = (const float*)d_in[4];
  const float* temperature = (const float*)d_in[5];

  char* ws = (char*)d_ws;
  ushort* xb   = (ushort*)(ws + 0);           // 33,554,432  (aliased by attnout later)
  ushort* wqb  = (ushort*)(ws + 33554432);    // 6,291,456
  ushort* wzb  = (ushort*)(ws + 39845888);    // 2,097,152
  ushort* qkvb = (ushort*)(ws + 41943040);    // 100,663,296
  float* invq  = (float*)(ws + 142606336);    // 16,384
  float* invk  = (float*)(ws + 142622720);    // 16,384
  float* npart = (float*)(ws + 142639104);    // 131,072
  float* Wpart = (float*)(ws + 142770176);    // 4,194,304
  ushort* attnout = xb;  // x is dead after QKV GEMM

  // 1) converts
  k_f2bf<<<dim3(16384), dim3(256), 0, stream>>>(x, xb, (MM * HIDD) / 4);
  k_f2bf<<<dim3(3072), dim3(256), 0, stream>>>(Wqkv, wqb, (NQKV * HIDD) / 4);
  k_f2bf<<<dim3(1024), dim3(256), 0, stream>>>(Wz, wzb, (HIDD * HIDD) / 4);

  // 2) QKV GEMM -> qkv bf16 [B,S,3072]
  k_gemm_bt<0><<<dim3(MM / 128, NQKV / 128), dim3(256), 0, stream>>>(
      xb, wqb, bqkv, (void*)qkvb, MM, NQKV, HIDD);

  // 3) norms
  k_norms_part<<<dim3(256), dim3(256), 0, stream>>>(qkvb, npart);
  k_norms_fin<<<dim3(16), dim3(256), 0, stream>>>(npart, invq, invk);

  // 4) gram partials, then fused softmax+PV
  k_gram_part<<<dim3(64, 4), dim3(256), 0, stream>>>(qkvb, Wpart);
  k_pv<<<dim3(64, 4), dim3(256), 0, stream>>>(qkvb, Wpart, invq, invk, temperature,
                                              attnout);

  // 5) output GEMM -> d_out fp32
  k_gemm_bt<1><<<dim3(MM / 128, HIDD / 128), dim3(256), 0, stream>>>(
      attnout, wzb, bz, d_out, MM, HIDD, HIDD);
}

// Round 3
// 268.762 us; speedup vs baseline: 1.5820x; 1.5820x over previous
//
#include <hip/hip_runtime.h>

#define DEVINL __device__ __forceinline__

// Problem constants
#define BB 4
#define SS 4096
#define HIDD 1024
#define HH 16
#define DH 64
#define NQKV 3072
#define MM (BB * SS)  // 16384

typedef __attribute__((ext_vector_type(8))) short bf16x8_t;
typedef __attribute__((ext_vector_type(4))) float f32x4_t;

typedef __attribute__((address_space(1))) const void GV;
typedef __attribute__((address_space(3))) void LV;

DEVINL void gload16(const void* g, void* l) {
  // async global->LDS, 16B/lane; LDS dest = wave-uniform base + lane*16
  __builtin_amdgcn_global_load_lds((GV*)g, (LV*)l, 16, 0, 0);
}

DEVINL float bf2f(ushort u) {
  union { unsigned int i; float f; } v;
  v.i = ((unsigned int)u) << 16;
  return v.f;
}
DEVINL ushort f2bf(float f) {
  unsigned int u = __float_as_uint(f);
  u = (u + 0x7fffu + ((u >> 16) & 1u)) >> 16;
  return (ushort)u;
}

// ---------------- fp32 -> bf16 convert (4 elems/thread) ----------------
__global__ __launch_bounds__(256) void k_f2bf(const float* __restrict__ src,
                                              ushort* __restrict__ dst, int n4) {
  int i = blockIdx.x * 256 + threadIdx.x;
  if (i >= n4) return;
  float4 v = ((const float4*)src)[i];
  ushort4 o;
  o.x = f2bf(v.x); o.y = f2bf(v.y); o.z = f2bf(v.z); o.w = f2bf(v.w);
  ((ushort4*)dst)[i] = o;
}

// ---------------- bf16 GEMM: C[M,N] = A[M,K] * B[N,K]^T + bias ----------------
// 128x128 tile, BK=64, 4 waves (2x2), each wave 4x4 frags of 16x16x32 MFMA.
// Staging: global_load_lds width=16, LINEAR LDS dest + pre-swizzled global
// source (chunk ^= row&7); reads use the same swizzle (rule #21).
// MODE 1: store fp32 natural C (+bias). MODE 2: QKV split epilogue —
//   cols <2048 -> transposed bf16 QT/KT [t][b][h][d][s]; cols >=2048 -> V natural.
template <int MODE>
__global__ __launch_bounds__(256) void k_gemm_bt(
    const ushort* __restrict__ A, const ushort* __restrict__ B,
    const float* __restrict__ bias, void* __restrict__ Cv,
    ushort* __restrict__ qT, ushort* __restrict__ vbuf,
    int M, int N, int K) {
  __shared__ ushort As[128 * 64];
  __shared__ ushort Bs[128 * 64];
  const int t = threadIdx.x;
  const int m0 = blockIdx.x * 128, n0 = blockIdx.y * 128;

  const int lane = t & 63, wave = t >> 6;
  const int wm = wave >> 1, wn = wave & 1;
  const int fr = lane & 15, g = lane >> 4;

  // staging lane constants: lane covers row-group rg*8 + rsub, 16B chunk (l&7)^rsub
  const int rsub = lane >> 3;
  const int gcol = ((lane & 7) ^ rsub) * 8;  // pre-swizzled global chunk (ushorts)

  f32x4_t acc[4][4] = {};
  for (int k0 = 0; k0 < K; k0 += 64) {
#pragma unroll
    for (int i = 0; i < 4; ++i) {
      int rg = wave * 4 + i;  // row-group 0..15 (8 rows = 1KB each)
      int row = rg * 8 + rsub;
      gload16(&A[(size_t)(m0 + row) * K + k0 + gcol], &As[rg * 512]);
      gload16(&B[(size_t)(n0 + row) * K + k0 + gcol], &Bs[rg * 512]);
    }
    __syncthreads();
#pragma unroll
    for (int kk = 0; kk < 2; ++kk) {
      bf16x8_t af[4], bfg[4];
#pragma unroll
      for (int mi = 0; mi < 4; ++mi) {
        int r = wm * 64 + mi * 16 + fr;
        af[mi] = *(const bf16x8_t*)&As[r * 64 + (((kk * 4 + g) ^ (r & 7)) * 8)];
      }
#pragma unroll
      for (int ni = 0; ni < 4; ++ni) {
        int r = wn * 64 + ni * 16 + fr;
        bfg[ni] = *(const bf16x8_t*)&Bs[r * 64 + (((kk * 4 + g) ^ (r & 7)) * 8)];
      }
#pragma unroll
      for (int mi = 0; mi < 4; ++mi)
#pragma unroll
        for (int ni = 0; ni < 4; ++ni)
          acc[mi][ni] = __builtin_amdgcn_mfma_f32_16x16x32_bf16(
              af[mi], bfg[ni], acc[mi][ni], 0, 0, 0);
    }
    __syncthreads();
  }
// epilogue: D col = lane&15, row = (lane>>4)*4 + reg (HW-verified mapping)
#pragma unroll
  for (int ni = 0; ni < 4; ++ni) {
    int col = n0 + wn * 64 + ni * 16 + fr;
    float bv = bias[col];
#pragma unroll
    for (int mi = 0; mi < 4; ++mi) {
      int rowbase = m0 + wm * 64 + mi * 16 + g * 4;
      if (MODE == 1) {
#pragma unroll
        for (int j = 0; j < 4; ++j)
          ((float*)Cv)[(size_t)(rowbase + j) * N + col] = acc[mi][ni][j] + bv;
      } else {
        ushort4 o;
        o.x = f2bf(acc[mi][ni][0] + bv);
        o.y = f2bf(acc[mi][ni][1] + bv);
        o.z = f2bf(acc[mi][ni][2] + bv);
        o.w = f2bf(acc[mi][ni][3] + bv);
        if (col < 2048) {
          int tt = col >> 10;           // 0=Q, 1=K
          int hh = (col >> 6) & 15;
          int d = col & 63;
          int b = rowbase >> 12;
          int s = rowbase & 4095;
          size_t off = ((((size_t)tt * BB + b) * HH + hh) * 64 + d) * SS + s;
          *(ushort4*)&qT[off] = o;     // 4 consecutive s
        } else {
          int c = col - 2048;
          vbuf[(size_t)(rowbase + 0) * HIDD + c] = o.x;
          vbuf[(size_t)(rowbase + 1) * HIDD + c] = o.y;
          vbuf[(size_t)(rowbase + 2) * HIDD + c] = o.z;
          vbuf[(size_t)(rowbase + 3) * HIDD + c] = o.w;
        }
      }
    }
  }
}

// ---------------- norms: one wave per (t,bh,d) row of QT/KT ----------------
__global__ __launch_bounds__(256) void k_norms(const ushort* __restrict__ qT,
                                               float* __restrict__ invq,
                                               float* __restrict__ invk) {
  int wave = threadIdx.x >> 6, lane = threadIdx.x & 63;
  int row = blockIdx.x * 4 + wave;  // 0..8191 (first 4096 = Q rows)
  const ushort* src = qT + (size_t)row * SS;
  float s = 0.f;
#pragma unroll
  for (int c = 0; c < 8; ++c) {
    bf16x8_t v = *(const bf16x8_t*)&src[c * 512 + lane * 8];
#pragma unroll
    for (int j = 0; j < 8; ++j) {
      float f = bf2f((ushort)v[j]);
      s += f * f;
    }
  }
#pragma unroll
  for (int off = 32; off; off >>= 1) s += __shfl_xor(s, off, 64);
  if (lane == 0) {
    float inv = 1.0f / fmaxf(sqrtf(s), 1e-12f);
    if (row < 4096) invq[row] = inv;
    else invk[row - 4096] = inv;
  }
}

// ---------------- gram partial via MFMA: Wpart[bh][p][d][e] ----------------
// block (bh,p): C[64 d][64 e] = sum_{s in quarter p} QT[d,s] * KT[e,s]
__global__ __launch_bounds__(256) void k_gram(const ushort* __restrict__ qT,
                                              float* __restrict__ Wpart) {
  __shared__ ushort Qs[64 * 64];
  __shared__ ushort Ks[64 * 64];
  int bh = blockIdx.x, p = blockIdx.y;
  const ushort* Qp = qT + (size_t)bh * 64 * SS + p * 1024;
  const ushort* Kp = qT + (size_t)(BB * HH + bh) * 64 * SS + p * 1024;
  const int t = threadIdx.x;
  const int lane = t & 63, w = t >> 6;
  const int fr = lane & 15, g = lane >> 4;
  const int rsub = lane >> 3;
  const int gcol = ((lane & 7) ^ rsub) * 8;
  f32x4_t acc[4] = {};
  for (int sc = 0; sc < 16; ++sc) {
#pragma unroll
    for (int i = 0; i < 2; ++i) {
      int rg = w * 2 + i;  // 0..7
      int row = rg * 8 + rsub;
      gload16(&Qp[(size_t)row * SS + sc * 64 + gcol], &Qs[rg * 512]);
      gload16(&Kp[(size_t)row * SS + sc * 64 + gcol], &Ks[rg * 512]);
    }
    __syncthreads();
#pragma unroll
    for (int kk = 0; kk < 2; ++kk) {
      int r = w * 16 + fr;
      bf16x8_t af = *(const bf16x8_t*)&Qs[r * 64 + (((kk * 4 + g) ^ (r & 7)) * 8)];
#pragma unroll
      for (int ni = 0; ni < 4; ++ni) {
        int r2 = ni * 16 + fr;
        bf16x8_t bfg = *(const bf16x8_t*)&Ks[r2 * 64 + (((kk * 4 + g) ^ (r2 & 7)) * 8)];
        acc[ni] = __builtin_amdgcn_mfma_f32_16x16x32_bf16(af, bfg, acc[ni], 0, 0, 0);
      }
    }
    __syncthreads();
  }
  float* wp = Wpart + (size_t)(bh * 4 + p) * 4096;
#pragma unroll
  for (int ni = 0; ni < 4; ++ni)
#pragma unroll
    for (int j = 0; j < 4; ++j)
      wp[(w * 16 + g * 4 + j) * 64 + ni * 16 + fr] = acc[ni][j];
}

// ---------------- fused scale + softmax + PV (MFMA) ----------------
// block (bh,p): rebuild W, softmax rows -> bf16 attn; then per s-chunk:
// C[s 16][d 64] = sum_e V[s,e]*attn[d,e] via mfma (A=V natural, B=attn rows).
__global__ __launch_bounds__(256) void k_pv(const ushort* __restrict__ vbuf,
                                            const float* __restrict__ Wpart,
                                            const float* __restrict__ invq,
                                            const float* __restrict__ invk,
                                            const float* __restrict__ temperature,
                                            ushort* __restrict__ attnout) {
  __shared__ float attnf[64][65];
  __shared__ ushort attnb[64 * 72];  // stride 72 kills frag-read conflicts
  __shared__ ushort Vs[64 * 64];
  int bh = blockIdx.x, p = blockIdx.y;
  int b = bh >> 4, h = bh & 15;
  const int t = threadIdx.x;
  const int lane = t & 63, w = t >> 6;
  const int fr = lane & 15, g = lane >> 4;
  const int rsub = lane >> 3;
  const int gcol = ((lane & 7) ^ rsub) * 8;
  float tscale = temperature[h] * (1.0f / 32.0f);  // / sqrt(HID)
  for (int idx = t; idx < 4096; idx += 256) {
    int d = idx >> 6, e = idx & 63;
    float s = 0.f;
#pragma unroll
    for (int q = 0; q < 4; ++q) s += Wpart[(size_t)(bh * 4 + q) * 4096 + idx];
    attnf[d][e] = s * invq[bh * 64 + d] * invk[bh * 64 + e] * tscale;
  }
  __syncthreads();
  if (t < 64) {
    float m = -1e30f;
#pragma unroll 8
    for (int e = 0; e < 64; ++e) m = fmaxf(m, attnf[t][e]);
    float sum = 0.f;
#pragma unroll 8
    for (int e = 0; e < 64; ++e) {
      float v = __expf(attnf[t][e] - m);
      attnf[t][e] = v;
      sum += v;
    }
    float inv = 1.0f / sum;
#pragma unroll 8
    for (int e = 0; e < 64; ++e) attnb[t * 72 + e] = f2bf(attnf[t][e] * inv);
  }
  __syncthreads();
  // hoist B-frags (attn rows, loop-invariant): col d = ni*16+fr, k = e
  bf16x8_t bfg[4][2];
#pragma unroll
  for (int ni = 0; ni < 4; ++ni)
#pragma unroll
    for (int kk = 0; kk < 2; ++kk)
      bfg[ni][kk] = *(const bf16x8_t*)&attnb[(ni * 16 + fr) * 72 + (kk * 4 + g) * 8];

  const ushort* vb = vbuf + (size_t)(b * SS + p * 1024) * HIDD + h * 64;
  ushort* ob = attnout + (size_t)(b * SS + p * 1024) * HIDD + h * 64;
  for (int s0 = 0; s0 < 1024; s0 += 64) {
#pragma unroll
    for (int i = 0; i < 2; ++i) {
      int rg = w * 2 + i;
      int row = rg * 8 + rsub;
      gload16(&vb[(size_t)(s0 + row) * HIDD + gcol], &Vs[rg * 512]);
    }
    __syncthreads();
    f32x4_t acc[4] = {};
#pragma unroll
    for (int kk = 0; kk < 2; ++kk) {
      int r = w * 16 + fr;  // s-row within chunk
      bf16x8_t af = *(const bf16x8_t*)&Vs[r * 64 + (((kk * 4 + g) ^ (r & 7)) * 8)];
#pragma unroll
      for (int ni = 0; ni < 4; ++ni)
        acc[ni] = __builtin_amdgcn_mfma_f32_16x16x32_bf16(af, bfg[ni][kk], acc[ni], 0, 0, 0);
    }
#pragma unroll
    for (int ni = 0; ni < 4; ++ni)
#pragma unroll
      for (int j = 0; j < 4; ++j)
        ob[(size_t)(s0 + w * 16 + g * 4 + j) * HIDD + ni * 16 + fr] = f2bf(acc[ni][j]);
    __syncthreads();
  }
}

extern "C" void kernel_launch(void* const* d_in, const int* in_sizes, int n_in,
                              void* d_out, int out_size, void* d_ws, size_t ws_size,
                              hipStream_t stream) {
  const float* x = (const float*)d_in[0];
  const float* Wqkv = (const float*)d_in[1];
  const float* bqkv = (const float*)d_in[2];
  const float* Wz = (const float*)d_in[3];
  const float* bz = (const float*)d_in[4];
  const float* temperature = (const float*)d_in[5];

  char* ws = (char*)d_ws;
  ushort* xb   = (ushort*)(ws + 0);           // 33,554,432 (alias: attnout)
  ushort* wqb  = (ushort*)(ws + 33554432);    // 6,291,456
  ushort* wzb  = (ushort*)(ws + 39845888);    // 2,097,152
  ushort* vbuf = (ushort*)(ws + 41943040);    // 33,554,432
  ushort* qkvT = (ushort*)(ws + 75497472);    // 67,108,864  [t][b][h][d][s]
  float* invq  = (float*)(ws + 142606336);    // 16,384
  float* invk  = (float*)(ws + 142622720);    // 16,384
  float* Wpart = (float*)(ws + 142639104);    // 4,194,304
  ushort* attnout = xb;  // x is dead after QKV GEMM

  // 1) converts
  k_f2bf<<<dim3(16384), dim3(256), 0, stream>>>(x, xb, (MM * HIDD) / 4);
  k_f2bf<<<dim3(3072), dim3(256), 0, stream>>>(Wqkv, wqb, (NQKV * HIDD) / 4);
  k_f2bf<<<dim3(1024), dim3(256), 0, stream>>>(Wz, wzb, (HIDD * HIDD) / 4);

  // 2) QKV GEMM -> QT/KT transposed + V natural
  k_gemm_bt<2><<<dim3(MM / 128, NQKV / 128), dim3(256), 0, stream>>>(
      xb, wqb, bqkv, nullptr, qkvT, vbuf, MM, NQKV, HIDD);

  // 3) gram partials (MFMA) + norms
  k_gram<<<dim3(64, 4), dim3(256), 0, stream>>>(qkvT, Wpart);
  k_norms<<<dim3(2048), dim3(256), 0, stream>>>(qkvT, invq, invk);

  // 4) fused softmax + PV (MFMA)
  k_pv<<<dim3(64, 4), dim3(256), 0, stream>>>(vbuf, Wpart, invq, invk, temperature,
                                              attnout);

  // 5) output GEMM -> d_out fp32
  k_gemm_bt<1><<<dim3(MM / 128, HIDD / 128), dim3(256), 0, stream>>>(
      attnout, wzb, bz, d_out, nullptr, nullptr, MM, HIDD, HIDD);
}

// Round 4
// 263.250 us; speedup vs baseline: 1.6152x; 1.0209x over previous
//
#include <hip/hip_runtime.h>

#define DEVINL __device__ __forceinline__

// Problem constants
#define BB 4
#define SS 4096
#define HIDD 1024
#define HH 16
#define DH 64
#define NQKV 3072
#define MM (BB * SS)  // 16384

typedef __attribute__((ext_vector_type(8))) short bf16x8_t;
typedef __attribute__((ext_vector_type(4))) float f32x4_t;

typedef __attribute__((address_space(1))) const void GV;
typedef __attribute__((address_space(3))) void LV;

DEVINL void gload16(const void* g, void* l) {
  // async global->LDS, 16B/lane; LDS dest = wave-uniform base + lane*16
  __builtin_amdgcn_global_load_lds((GV*)g, (LV*)l, 16, 0, 0);
}

DEVINL float bf2f(ushort u) {
  union { unsigned int i; float f; } v;
  v.i = ((unsigned int)u) << 16;
  return v.f;
}
DEVINL ushort f2bf(float f) {
  unsigned int u = __float_as_uint(f);
  u = (u + 0x7fffu + ((u >> 16) & 1u)) >> 16;
  return (ushort)u;
}

// ---------------- fp32 -> bf16 convert (4 elems/thread) ----------------
__global__ __launch_bounds__(256) void k_f2bf(const float* __restrict__ src,
                                              ushort* __restrict__ dst, int n4) {
  int i = blockIdx.x * 256 + threadIdx.x;
  if (i >= n4) return;
  float4 v = ((const float4*)src)[i];
  ushort4 o;
  o.x = f2bf(v.x); o.y = f2bf(v.y); o.z = f2bf(v.z); o.w = f2bf(v.w);
  ((ushort4*)dst)[i] = o;
}

// ---------------- bf16 GEMM: C[M,N] = A[M,K] * B[N,K]^T + bias ----------------
// 256x128 tile, BK=64, 8 waves (4M x 2N), each wave 64x64 out (4x4 frags).
// Triple-buffered LDS (144 KiB), counted-vmcnt pipeline: stage kt+2, wait
// vmcnt(12) (= 2 K-tiles in flight), raw s_barrier; never drain in main loop.
// Staging: global_load_lds width=16, LINEAR LDS dest + pre-swizzled global
// source (chunk ^= row&7); frag reads use the same swizzle (rule #21).
// MODE 1: store fp32 natural C (+bias). MODE 2: QKV split epilogue —
//   cols <2048 -> transposed bf16 QT/KT [t][b][h][d][s]; cols >=2048 -> V natural.
template <int MODE>
__global__ __launch_bounds__(512, 2) void k_gemm256(
    const ushort* __restrict__ A, const ushort* __restrict__ B,
    const float* __restrict__ bias, void* __restrict__ Cv,
    ushort* __restrict__ qT, ushort* __restrict__ vbuf,
    int M, int N, int K) {
  __shared__ ushort As[3][256 * 64];
  __shared__ ushort Bs[3][128 * 64];
  const int t = threadIdx.x;
  const int m0 = blockIdx.x * 256, n0 = blockIdx.y * 128;
  const int lane = t & 63, wid = t >> 6;
  const int wm = wid >> 1, wn = wid & 1;
  const int fr = lane & 15, g = lane >> 4;

  // staging source mapping: within an 8KiB call, thread t covers row t>>3,
  // pre-swizzled 16B chunk ((t&7) ^ (row&7)); LDS dest linear (wave-uniform base)
  const int srow = t >> 3;                        // 0..63
  const int schunk = ((t & 7) ^ (srow & 7)) * 8;  // ushort offset in row

  const int NT = K >> 6;

  f32x4_t acc[4][4] = {};

#define STAGE(KT)                                                              \
  {                                                                            \
    const int bufi_ = (KT) % 3;                                                \
    const int kc_ = (KT) * 64;                                                 \
    _Pragma("unroll") for (int c = 0; c < 4; ++c)                              \
        gload16(&A[(size_t)(m0 + c * 64 + srow) * K + kc_ + schunk],           \
                &As[bufi_][c * 4096 + wid * 512]);                             \
    _Pragma("unroll") for (int c = 0; c < 2; ++c)                              \
        gload16(&B[(size_t)(n0 + c * 64 + srow) * K + kc_ + schunk],           \
                &Bs[bufi_][c * 4096 + wid * 512]);                             \
  }

#define COMPUTE(KT)                                                            \
  {                                                                            \
    const int bufi_ = (KT) % 3;                                                \
    const ushort* As_ = As[bufi_];                                             \
    const ushort* Bs_ = Bs[bufi_];                                             \
    _Pragma("unroll") for (int kk = 0; kk < 2; ++kk) {                         \
      bf16x8_t af[4], bfg[4];                                                  \
      _Pragma("unroll") for (int mi = 0; mi < 4; ++mi) {                       \
        int r = wm * 64 + mi * 16 + fr;                                        \
        af[mi] = *(const bf16x8_t*)&As_[r * 64 + (((kk * 4 + g) ^ (r & 7)) * 8)]; \
      }                                                                        \
      _Pragma("unroll") for (int ni = 0; ni < 4; ++ni) {                       \
        int r = wn * 64 + ni * 16 + fr;                                        \
        bfg[ni] = *(const bf16x8_t*)&Bs_[r * 64 + (((kk * 4 + g) ^ (r & 7)) * 8)]; \
      }                                                                        \
      _Pragma("unroll") for (int mi = 0; mi < 4; ++mi)                         \
          _Pragma("unroll") for (int ni = 0; ni < 4; ++ni)                     \
              acc[mi][ni] = __builtin_amdgcn_mfma_f32_16x16x32_bf16(           \
                  af[mi], bfg[ni], acc[mi][ni], 0, 0, 0);                      \
    }                                                                          \
  }

  // prologue: stage tiles 0 and 1
  STAGE(0);
  STAGE(1);
  // main loop: stage kt+2, wait 2-tiles-in-flight, compute kt
  for (int kt = 0; kt < NT - 2; ++kt) {
    STAGE(kt + 2);
    asm volatile("s_waitcnt vmcnt(12)" ::: "memory");
    __builtin_amdgcn_s_barrier();
    __builtin_amdgcn_sched_barrier(0);
    COMPUTE(kt);
    __builtin_amdgcn_s_barrier();
  }
  // tail: kt = NT-2
  asm volatile("s_waitcnt vmcnt(6)" ::: "memory");
  __builtin_amdgcn_s_barrier();
  __builtin_amdgcn_sched_barrier(0);
  COMPUTE(NT - 2);
  __builtin_amdgcn_s_barrier();
  // tail: kt = NT-1
  asm volatile("s_waitcnt vmcnt(0)" ::: "memory");
  __builtin_amdgcn_s_barrier();
  __builtin_amdgcn_sched_barrier(0);
  COMPUTE(NT - 1);
#undef STAGE
#undef COMPUTE

  // epilogue: D col = lane&15, row = (lane>>4)*4 + reg (HW-verified mapping)
#pragma unroll
  for (int ni = 0; ni < 4; ++ni) {
    int col = n0 + wn * 64 + ni * 16 + fr;
    float bv = bias[col];
#pragma unroll
    for (int mi = 0; mi < 4; ++mi) {
      int rowbase = m0 + wm * 64 + mi * 16 + g * 4;
      if (MODE == 1) {
#pragma unroll
        for (int j = 0; j < 4; ++j)
          ((float*)Cv)[(size_t)(rowbase + j) * N + col] = acc[mi][ni][j] + bv;
      } else {
        ushort4 o;
        o.x = f2bf(acc[mi][ni][0] + bv);
        o.y = f2bf(acc[mi][ni][1] + bv);
        o.z = f2bf(acc[mi][ni][2] + bv);
        o.w = f2bf(acc[mi][ni][3] + bv);
        if (col < 2048) {
          int tt = col >> 10;           // 0=Q, 1=K
          int hh = (col >> 6) & 15;
          int d = col & 63;
          int b = rowbase >> 12;
          int s = rowbase & 4095;
          size_t off = ((((size_t)tt * BB + b) * HH + hh) * 64 + d) * SS + s;
          *(ushort4*)&qT[off] = o;     // 4 consecutive s
        } else {
          int c = col - 2048;
          vbuf[(size_t)(rowbase + 0) * HIDD + c] = o.x;
          vbuf[(size_t)(rowbase + 1) * HIDD + c] = o.y;
          vbuf[(size_t)(rowbase + 2) * HIDD + c] = o.z;
          vbuf[(size_t)(rowbase + 3) * HIDD + c] = o.w;
        }
      }
    }
  }
}

// ---------------- norms: one wave per (t,bh,d) row of QT/KT ----------------
__global__ __launch_bounds__(256) void k_norms(const ushort* __restrict__ qT,
                                               float* __restrict__ invq,
                                               float* __restrict__ invk) {
  int wave = threadIdx.x >> 6, lane = threadIdx.x & 63;
  int row = blockIdx.x * 4 + wave;  // 0..8191 (first 4096 = Q rows)
  const ushort* src = qT + (size_t)row * SS;
  float s = 0.f;
#pragma unroll
  for (int c = 0; c < 8; ++c) {
    bf16x8_t v = *(const bf16x8_t*)&src[c * 512 + lane * 8];
#pragma unroll
    for (int j = 0; j < 8; ++j) {
      float f = bf2f((ushort)v[j]);
      s += f * f;
    }
  }
#pragma unroll
  for (int off = 32; off; off >>= 1) s += __shfl_xor(s, off, 64);
  if (lane == 0) {
    float inv = 1.0f / fmaxf(sqrtf(s), 1e-12f);
    if (row < 4096) invq[row] = inv;
    else invk[row - 4096] = inv;
  }
}

// ---------------- gram partial via MFMA: Wpart[bh][p][d][e] ----------------
// block (bh,p): C[64 d][64 e] = sum_{s in quarter p} QT[d,s] * KT[e,s]
__global__ __launch_bounds__(256) void k_gram(const ushort* __restrict__ qT,
                                              float* __restrict__ Wpart) {
  __shared__ ushort Qs[64 * 64];
  __shared__ ushort Ks[64 * 64];
  int bh = blockIdx.x, p = blockIdx.y;
  const ushort* Qp = qT + (size_t)bh * 64 * SS + p * 1024;
  const ushort* Kp = qT + (size_t)(BB * HH + bh) * 64 * SS + p * 1024;
  const int t = threadIdx.x;
  const int lane = t & 63, w = t >> 6;
  const int fr = lane & 15, g = lane >> 4;
  const int rsub = lane >> 3;
  const int gcol = ((lane & 7) ^ rsub) * 8;
  f32x4_t acc[4] = {};
  for (int sc = 0; sc < 16; ++sc) {
#pragma unroll
    for (int i = 0; i < 2; ++i) {
      int rg = w * 2 + i;  // 0..7
      int row = rg * 8 + rsub;
      gload16(&Qp[(size_t)row * SS + sc * 64 + gcol], &Qs[rg * 512]);
      gload16(&Kp[(size_t)row * SS + sc * 64 + gcol], &Ks[rg * 512]);
    }
    __syncthreads();
#pragma unroll
    for (int kk = 0; kk < 2; ++kk) {
      int r = w * 16 + fr;
      bf16x8_t af = *(const bf16x8_t*)&Qs[r * 64 + (((kk * 4 + g) ^ (r & 7)) * 8)];
#pragma unroll
      for (int ni = 0; ni < 4; ++ni) {
        int r2 = ni * 16 + fr;
        bf16x8_t bfg = *(const bf16x8_t*)&Ks[r2 * 64 + (((kk * 4 + g) ^ (r2 & 7)) * 8)];
        acc[ni] = __builtin_amdgcn_mfma_f32_16x16x32_bf16(af, bfg, acc[ni], 0, 0, 0);
      }
    }
    __syncthreads();
  }
  float* wp = Wpart + (size_t)(bh * 4 + p) * 4096;
#pragma unroll
  for (int ni = 0; ni < 4; ++ni)
#pragma unroll
    for (int j = 0; j < 4; ++j)
      wp[(w * 16 + g * 4 + j) * 64 + ni * 16 + fr] = acc[ni][j];
}

// ---------------- fused scale + softmax + PV (MFMA) ----------------
// block (bh,p): rebuild W, softmax rows -> bf16 attn; then per s-chunk:
// C[s 16][d 64] = sum_e V[s,e]*attn[d,e] via mfma (A=V natural, B=attn rows).
__global__ __launch_bounds__(256) void k_pv(const ushort* __restrict__ vbuf,
                                            const float* __restrict__ Wpart,
                                            const float* __restrict__ invq,
                                            const float* __restrict__ invk,
                                            const float* __restrict__ temperature,
                                            ushort* __restrict__ attnout) {
  __shared__ float attnf[64][65];
  __shared__ ushort attnb[64 * 72];  // stride 72 kills frag-read conflicts
  __shared__ ushort Vs[64 * 64];
  int bh = blockIdx.x, p = blockIdx.y;
  int b = bh >> 4, h = bh & 15;
  const int t = threadIdx.x;
  const int lane = t & 63, w = t >> 6;
  const int fr = lane & 15, g = lane >> 4;
  const int rsub = lane >> 3;
  const int gcol = ((lane & 7) ^ rsub) * 8;
  float tscale = temperature[h] * (1.0f / 32.0f);  // / sqrt(HID)
  for (int idx = t; idx < 4096; idx += 256) {
    int d = idx >> 6, e = idx & 63;
    float s = 0.f;
#pragma unroll
    for (int q = 0; q < 4; ++q) s += Wpart[(size_t)(bh * 4 + q) * 4096 + idx];
    attnf[d][e] = s * invq[bh * 64 + d] * invk[bh * 64 + e] * tscale;
  }
  __syncthreads();
  if (t < 64) {
    float m = -1e30f;
#pragma unroll 8
    for (int e = 0; e < 64; ++e) m = fmaxf(m, attnf[t][e]);
    float sum = 0.f;
#pragma unroll 8
    for (int e = 0; e < 64; ++e) {
      float v = __expf(attnf[t][e] - m);
      attnf[t][e] = v;
      sum += v;
    }
    float inv = 1.0f / sum;
#pragma unroll 8
    for (int e = 0; e < 64; ++e) attnb[t * 72 + e] = f2bf(attnf[t][e] * inv);
  }
  __syncthreads();
  // hoist B-frags (attn rows, loop-invariant): col d = ni*16+fr, k = e
  bf16x8_t bfg[4][2];
#pragma unroll
  for (int ni = 0; ni < 4; ++ni)
#pragma unroll
    for (int kk = 0; kk < 2; ++kk)
      bfg[ni][kk] = *(const bf16x8_t*)&attnb[(ni * 16 + fr) * 72 + (kk * 4 + g) * 8];

  const ushort* vb = vbuf + (size_t)(b * SS + p * 1024) * HIDD + h * 64;
  ushort* ob = attnout + (size_t)(b * SS + p * 1024) * HIDD + h * 64;
  for (int s0 = 0; s0 < 1024; s0 += 64) {
#pragma unroll
    for (int i = 0; i < 2; ++i) {
      int rg = w * 2 + i;
      int row = rg * 8 + rsub;
      gload16(&vb[(size_t)(s0 + row) * HIDD + gcol], &Vs[rg * 512]);
    }
    __syncthreads();
    f32x4_t acc[4] = {};
#pragma unroll
    for (int kk = 0; kk < 2; ++kk) {
      int r = w * 16 + fr;  // s-row within chunk
      bf16x8_t af = *(const bf16x8_t*)&Vs[r * 64 + (((kk * 4 + g) ^ (r & 7)) * 8)];
#pragma unroll
      for (int ni = 0; ni < 4; ++ni)
        acc[ni] = __builtin_amdgcn_mfma_f32_16x16x32_bf16(af, bfg[ni][kk], acc[ni], 0, 0, 0);
    }
#pragma unroll
    for (int ni = 0; ni < 4; ++ni)
#pragma unroll
      for (int j = 0; j < 4; ++j)
        ob[(size_t)(s0 + w * 16 + g * 4 + j) * HIDD + ni * 16 + fr] = f2bf(acc[ni][j]);
    __syncthreads();
  }
}

extern "C" void kernel_launch(void* const* d_in, const int* in_sizes, int n_in,
                              void* d_out, int out_size, void* d_ws, size_t ws_size,
                              hipStream_t stream) {
  const float* x = (const float*)d_in[0];
  const float* Wqkv = (const float*)d_in[1];
  const float* bqkv = (const float*)d_in[2];
  const float* Wz = (const float*)d_in[3];
  const float* bz = (const float*)d_in[4];
  const float* temperature = (const float*)d_in[5];

  char* ws = (char*)d_ws;
  ushort* xb   = (ushort*)(ws + 0);           // 33,554,432 (alias: attnout)
  ushort* wqb  = (ushort*)(ws + 33554432);    // 6,291,456
  ushort* wzb  = (ushort*)(ws + 39845888);    // 2,097,152
  ushort* vbuf = (ushort*)(ws + 41943040);    // 33,554,432
  ushort* qkvT = (ushort*)(ws + 75497472);    // 67,108,864  [t][b][h][d][s]
  float* invq  = (float*)(ws + 142606336);    // 16,384
  float* invk  = (float*)(ws + 142622720);    // 16,384
  float* Wpart = (float*)(ws + 142639104);    // 4,194,304
  ushort* attnout = xb;  // x is dead after QKV GEMM

  // 1) converts
  k_f2bf<<<dim3(16384), dim3(256), 0, stream>>>(x, xb, (MM * HIDD) / 4);
  k_f2bf<<<dim3(3072), dim3(256), 0, stream>>>(Wqkv, wqb, (NQKV * HIDD) / 4);
  k_f2bf<<<dim3(1024), dim3(256), 0, stream>>>(Wz, wzb, (HIDD * HIDD) / 4);

  // 2) QKV GEMM -> QT/KT transposed + V natural
  k_gemm256<2><<<dim3(MM / 256, NQKV / 128), dim3(512), 0, stream>>>(
      xb, wqb, bqkv, nullptr, qkvT, vbuf, MM, NQKV, HIDD);

  // 3) gram partials (MFMA) + norms
  k_gram<<<dim3(64, 4), dim3(256), 0, stream>>>(qkvT, Wpart);
  k_norms<<<dim3(2048), dim3(256), 0, stream>>>(qkvT, invq, invk);

  // 4) fused softmax + PV (MFMA)
  k_pv<<<dim3(64, 4), dim3(256), 0, stream>>>(vbuf, Wpart, invq, invk, temperature,
                                              attnout);

  // 5) output GEMM -> d_out fp32
  k_gemm256<1><<<dim3(MM / 256, HIDD / 128), dim3(512), 0, stream>>>(
      attnout, wzb, bz, d_out, nullptr, nullptr, MM, HIDD, HIDD);
}

// Round 5
// 238.139 us; speedup vs baseline: 1.7855x; 1.1054x over previous
//
#include <hip/hip_runtime.h>

#define DEVINL __device__ __forceinline__

// Problem constants
#define BB 4
#define SS 4096
#define HIDD 1024
#define HH 16
#define DH 64
#define NQKV 3072
#define MM (BB * SS)  // 16384

typedef __attribute__((ext_vector_type(8))) short bf16x8_t;
typedef __attribute__((ext_vector_type(4))) float f32x4_t;

typedef __attribute__((address_space(1))) const void GV;
typedef __attribute__((address_space(3))) void LV;

DEVINL void gload16(const void* g, void* l) {
  // async global->LDS, 16B/lane; LDS dest = wave-uniform base + lane*16
  __builtin_amdgcn_global_load_lds((GV*)g, (LV*)l, 16, 0, 0);
}

DEVINL float bf2f(ushort u) {
  union { unsigned int i; float f; } v;
  v.i = ((unsigned int)u) << 16;
  return v.f;
}
DEVINL ushort f2bf(float f) {
  unsigned int u = __float_as_uint(f);
  u = (u + 0x7fffu + ((u >> 16) & 1u)) >> 16;
  return (ushort)u;
}

// ---------------- fp32 -> bf16 convert (4 elems/thread) ----------------
__global__ __launch_bounds__(256) void k_f2bf(const float* __restrict__ src,
                                              ushort* __restrict__ dst, int n4) {
  int i = blockIdx.x * 256 + threadIdx.x;
  if (i >= n4) return;
  float4 v = ((const float4*)src)[i];
  ushort4 o;
  o.x = f2bf(v.x); o.y = f2bf(v.y); o.z = f2bf(v.z); o.w = f2bf(v.w);
  ((ushort4*)dst)[i] = o;
}

// ---------------- 8-phase 256x256 bf16 GEMM: C = A[M,K] * B[N,K]^T + bias ----
// 8 waves (2M x 4N), BK=64, acc 8x4 frags of 16x16x32. LDS: 2 K-tile slots
// for A and B (32 KB each) + 8 KB dummy for tail stages = 136 KB.
// Per phase: {ds_read A-quad (+B at quad0) | stage 1 half-tile} barrier
// lgkmcnt(0) schedbar setprio MFMA*16 setprio [vmcnt(4) @ ph3/ph7] barrier.
// Swizzle: 16B chunk ^= (row&7) on both the pre-swizzled global source and
// the LDS frag reads (rule #21). MODE 1: fp32 natural C. MODE 2: QKV split.
template <int MODE>
__global__ __launch_bounds__(512, 2) void k_gemm8p(
    const ushort* __restrict__ A, const ushort* __restrict__ B,
    const float* __restrict__ bias, void* __restrict__ Cv,
    ushort* __restrict__ qT, ushort* __restrict__ vbuf,
    int M, int N, int K) {
  __shared__ ushort As0[256 * 64];
  __shared__ ushort As1[256 * 64];
  __shared__ ushort Bs0[256 * 64];
  __shared__ ushort Bs1[256 * 64];
  __shared__ ushort Dmy[4096];
  const int t = threadIdx.x;
  const int m0 = blockIdx.x * 256, n0 = blockIdx.y * 256;
  const int lane = t & 63, wid = t >> 6;
  const int wm = wid >> 2, wn = wid & 3;   // 2M x 4N waves
  const int fr = lane & 15, g = lane >> 4;
  const int srow = t >> 3;                        // 0..63 (row within 64-row call)
  const int schunk = ((t & 7) ^ (srow & 7)) * 8;  // pre-swizzled 16B chunk
  const int NT = K >> 6;
  const ushort* Ag = A + (size_t)m0 * K;
  const ushort* Bg = B + (size_t)n0 * K;

  f32x4_t acc[8][4] = {};
  bf16x8_t af[2][2], bfr[4][2];

  // stage half-tile hf (0/1 = rows 0-127 / 128-255) of K-tile `tile` from gsrc
  // into LDS slot ls_ (2 gload calls, 64 rows each). tile >= NT -> dummy.
#define STG(ls_, gsrc, tile, hf)                                            \
  {                                                                         \
    if ((tile) < NT) {                                                      \
      const ushort* gs_ = (gsrc) + (size_t)((hf) * 128 + srow) * K +        \
                          (tile) * 64 + schunk;                             \
      ushort* ld_ = (ls_) + ((hf) * 128 + wid * 8) * 64;                    \
      gload16(gs_, ld_);                                                    \
      gload16(gs_ + (size_t)64 * K, ld_ + 64 * 64);                         \
    } else {                                                                \
      const ushort* gs_ = (gsrc) + (size_t)srow * K + schunk;               \
      ushort* ld_ = Dmy + wid * 512;                                        \
      gload16(gs_, ld_);                                                    \
      gload16(gs_, ld_);                                                    \
    }                                                                       \
  }

#define LDA(as_, q)                                                         \
  _Pragma("unroll") for (int ii = 0; ii < 2; ++ii)                          \
  _Pragma("unroll") for (int kk = 0; kk < 2; ++kk) {                        \
    int r = wm * 128 + ((q) * 2 + ii) * 16 + fr;                            \
    af[ii][kk] = *(const bf16x8_t*)&(as_)[r * 64 + (((kk * 4 + g) ^ (r & 7)) * 8)]; \
  }

#define LDB(bs_)                                                            \
  _Pragma("unroll") for (int ni = 0; ni < 4; ++ni)                          \
  _Pragma("unroll") for (int kk = 0; kk < 2; ++kk) {                        \
    int r = wn * 64 + ni * 16 + fr;                                         \
    bfr[ni][kk] = *(const bf16x8_t*)&(bs_)[r * 64 + (((kk * 4 + g) ^ (r & 7)) * 8)]; \
  }

#define MMA(q)                                                              \
  _Pragma("unroll") for (int kk = 0; kk < 2; ++kk)                          \
  _Pragma("unroll") for (int ii = 0; ii < 2; ++ii)                          \
  _Pragma("unroll") for (int ni = 0; ni < 4; ++ni)                          \
    acc[(q) * 2 + ii][ni] = __builtin_amdgcn_mfma_f32_16x16x32_bf16(        \
        af[ii][kk], bfr[ni][kk], acc[(q) * 2 + ii][ni], 0, 0, 0);

#define BAR1                                                                \
  __builtin_amdgcn_s_barrier();                                             \
  asm volatile("s_waitcnt lgkmcnt(0)" ::: "memory");                        \
  __builtin_amdgcn_sched_barrier(0);                                        \
  __builtin_amdgcn_s_setprio(1);

#define BAR2                                                                \
  __builtin_amdgcn_s_setprio(0);                                            \
  __builtin_amdgcn_s_barrier();                                             \
  __builtin_amdgcn_sched_barrier(0);

#define BAR2VM                                                              \
  __builtin_amdgcn_s_setprio(0);                                            \
  asm volatile("s_waitcnt vmcnt(4)" ::: "memory");                          \
  __builtin_amdgcn_s_barrier();                                             \
  __builtin_amdgcn_sched_barrier(0);

  // prologue: B(0), A(0), B(1) fully staged; loop ph0/ph1 stage A(1).
  STG(Bs0, Bg, 0, 0); STG(Bs0, Bg, 0, 1);
  STG(As0, Ag, 0, 0); STG(As0, Ag, 0, 1);
  STG(Bs1, Bg, 1, 0); STG(Bs1, Bg, 1, 1);
  asm volatile("s_waitcnt vmcnt(4)" ::: "memory");
  __builtin_amdgcn_s_barrier();
  __builtin_amdgcn_sched_barrier(0);

  for (int J = 0; J < (NT >> 1); ++J) {
    const int T0 = 2 * J, T1 = 2 * J + 1;
    // ph0
    LDA(As0, 0); LDB(Bs0); STG(As1, Ag, T1, 0);
    BAR1; MMA(0); BAR2;
    // ph1
    LDA(As0, 1); STG(As1, Ag, T1, 1);
    BAR1; MMA(1); BAR2;
    // ph2
    LDA(As0, 2); STG(Bs0, Bg, T0 + 2, 0);
    BAR1; MMA(2); BAR2;
    // ph3
    LDA(As0, 3); STG(Bs0, Bg, T0 + 2, 1);
    BAR1; MMA(3); BAR2VM;
    // ph4
    LDA(As1, 0); LDB(Bs1); STG(As0, Ag, T0 + 2, 0);
    BAR1; MMA(0); BAR2;
    // ph5
    LDA(As1, 1); STG(As0, Ag, T0 + 2, 1);
    BAR1; MMA(1); BAR2;
    // ph6
    LDA(As1, 2); STG(Bs1, Bg, T1 + 2, 0);
    BAR1; MMA(2); BAR2;
    // ph7
    LDA(As1, 3); STG(Bs1, Bg, T1 + 2, 1);
    BAR1; MMA(3); BAR2VM;
  }
#undef STG
#undef LDA
#undef LDB
#undef MMA
#undef BAR1
#undef BAR2
#undef BAR2VM

  // epilogue: D col = lane&15, row = (lane>>4)*4 + reg (HW-verified mapping)
#pragma unroll
  for (int ni = 0; ni < 4; ++ni) {
    int col = n0 + wn * 64 + ni * 16 + fr;
    float bv = bias[col];
#pragma unroll
    for (int mi = 0; mi < 8; ++mi) {
      int rowbase = m0 + wm * 128 + mi * 16 + g * 4;
      if (MODE == 1) {
#pragma unroll
        for (int j = 0; j < 4; ++j)
          ((float*)Cv)[(size_t)(rowbase + j) * N + col] = acc[mi][ni][j] + bv;
      } else {
        ushort4 o;
        o.x = f2bf(acc[mi][ni][0] + bv);
        o.y = f2bf(acc[mi][ni][1] + bv);
        o.z = f2bf(acc[mi][ni][2] + bv);
        o.w = f2bf(acc[mi][ni][3] + bv);
        if (col < 2048) {
          int tt = col >> 10;           // 0=Q, 1=K
          int hh = (col >> 6) & 15;
          int d = col & 63;
          int b = rowbase >> 12;
          int s = rowbase & 4095;
          size_t off = ((((size_t)tt * BB + b) * HH + hh) * 64 + d) * SS + s;
          *(ushort4*)&qT[off] = o;     // 4 consecutive s
        } else {
          int c = col - 2048;
          vbuf[(size_t)(rowbase + 0) * HIDD + c] = o.x;
          vbuf[(size_t)(rowbase + 1) * HIDD + c] = o.y;
          vbuf[(size_t)(rowbase + 2) * HIDD + c] = o.z;
          vbuf[(size_t)(rowbase + 3) * HIDD + c] = o.w;
        }
      }
    }
  }
}

// ---------------- norms: one wave per (t,bh,d) row of QT/KT ----------------
__global__ __launch_bounds__(256) void k_norms(const ushort* __restrict__ qT,
                                               float* __restrict__ invq,
                                               float* __restrict__ invk) {
  int wave = threadIdx.x >> 6, lane = threadIdx.x & 63;
  int row = blockIdx.x * 4 + wave;  // 0..8191 (first 4096 = Q rows)
  const ushort* src = qT + (size_t)row * SS;
  float s = 0.f;
#pragma unroll
  for (int c = 0; c < 8; ++c) {
    bf16x8_t v = *(const bf16x8_t*)&src[c * 512 + lane * 8];
#pragma unroll
    for (int j = 0; j < 8; ++j) {
      float f = bf2f((ushort)v[j]);
      s += f * f;
    }
  }
#pragma unroll
  for (int off = 32; off; off >>= 1) s += __shfl_xor(s, off, 64);
  if (lane == 0) {
    float inv = 1.0f / fmaxf(sqrtf(s), 1e-12f);
    if (row < 4096) invq[row] = inv;
    else invk[row - 4096] = inv;
  }
}

// ---------------- gram partial via MFMA: Wpart[bh][p][d][e] ----------------
__global__ __launch_bounds__(256) void k_gram(const ushort* __restrict__ qT,
                                              float* __restrict__ Wpart) {
  __shared__ ushort Qs[64 * 64];
  __shared__ ushort Ks[64 * 64];
  int bh = blockIdx.x, p = blockIdx.y;
  const ushort* Qp = qT + (size_t)bh * 64 * SS + p * 1024;
  const ushort* Kp = qT + (size_t)(BB * HH + bh) * 64 * SS + p * 1024;
  const int t = threadIdx.x;
  const int lane = t & 63, w = t >> 6;
  const int fr = lane & 15, g = lane >> 4;
  const int rsub = lane >> 3;
  const int gcol = ((lane & 7) ^ rsub) * 8;
  f32x4_t acc[4] = {};
  for (int sc = 0; sc < 16; ++sc) {
#pragma unroll
    for (int i = 0; i < 2; ++i) {
      int rg = w * 2 + i;  // 0..7
      int row = rg * 8 + rsub;
      gload16(&Qp[(size_t)row * SS + sc * 64 + gcol], &Qs[rg * 512]);
      gload16(&Kp[(size_t)row * SS + sc * 64 + gcol], &Ks[rg * 512]);
    }
    __syncthreads();
#pragma unroll
    for (int kk = 0; kk < 2; ++kk) {
      int r = w * 16 + fr;
      bf16x8_t af = *(const bf16x8_t*)&Qs[r * 64 + (((kk * 4 + g) ^ (r & 7)) * 8)];
#pragma unroll
      for (int ni = 0; ni < 4; ++ni) {
        int r2 = ni * 16 + fr;
        bf16x8_t bfg = *(const bf16x8_t*)&Ks[r2 * 64 + (((kk * 4 + g) ^ (r2 & 7)) * 8)];
        acc[ni] = __builtin_amdgcn_mfma_f32_16x16x32_bf16(af, bfg, acc[ni], 0, 0, 0);
      }
    }
    __syncthreads();
  }
  float* wp = Wpart + (size_t)(bh * 4 + p) * 4096;
#pragma unroll
  for (int ni = 0; ni < 4; ++ni)
#pragma unroll
    for (int j = 0; j < 4; ++j)
      wp[(w * 16 + g * 4 + j) * 64 + ni * 16 + fr] = acc[ni][j];
}

// ---------------- fused scale + softmax + PV (MFMA) ----------------
__global__ __launch_bounds__(256) void k_pv(const ushort* __restrict__ vbuf,
                                            const float* __restrict__ Wpart,
                                            const float* __restrict__ invq,
                                            const float* __restrict__ invk,
                                            const float* __restrict__ temperature,
                                            ushort* __restrict__ attnout) {
  __shared__ float attnf[64][65];
  __shared__ ushort attnb[64 * 72];  // stride 72 kills frag-read conflicts
  __shared__ ushort Vs[64 * 64];
  int bh = blockIdx.x, p = blockIdx.y;
  int b = bh >> 4, h = bh & 15;
  const int t = threadIdx.x;
  const int lane = t & 63, w = t >> 6;
  const int fr = lane & 15, g = lane >> 4;
  const int rsub = lane >> 3;
  const int gcol = ((lane & 7) ^ rsub) * 8;
  float tscale = temperature[h] * (1.0f / 32.0f);  // / sqrt(HID)
  for (int idx = t; idx < 4096; idx += 256) {
    int d = idx >> 6, e = idx & 63;
    float s = 0.f;
#pragma unroll
    for (int q = 0; q < 4; ++q) s += Wpart[(size_t)(bh * 4 + q) * 4096 + idx];
    attnf[d][e] = s * invq[bh * 64 + d] * invk[bh * 64 + e] * tscale;
  }
  __syncthreads();
  if (t < 64) {
    float m = -1e30f;
#pragma unroll 8
    for (int e = 0; e < 64; ++e) m = fmaxf(m, attnf[t][e]);
    float sum = 0.f;
#pragma unroll 8
    for (int e = 0; e < 64; ++e) {
      float v = __expf(attnf[t][e] - m);
      attnf[t][e] = v;
      sum += v;
    }
    float inv = 1.0f / sum;
#pragma unroll 8
    for (int e = 0; e < 64; ++e) attnb[t * 72 + e] = f2bf(attnf[t][e] * inv);
  }
  __syncthreads();
  // hoist B-frags (attn rows, loop-invariant): col d = ni*16+fr, k = e
  bf16x8_t bfg[4][2];
#pragma unroll
  for (int ni = 0; ni < 4; ++ni)
#pragma unroll
    for (int kk = 0; kk < 2; ++kk)
      bfg[ni][kk] = *(const bf16x8_t*)&attnb[(ni * 16 + fr) * 72 + (kk * 4 + g) * 8];

  const ushort* vb = vbuf + (size_t)(b * SS + p * 1024) * HIDD + h * 64;
  ushort* ob = attnout + (size_t)(b * SS + p * 1024) * HIDD + h * 64;
  for (int s0 = 0; s0 < 1024; s0 += 64) {
#pragma unroll
    for (int i = 0; i < 2; ++i) {
      int rg = w * 2 + i;
      int row = rg * 8 + rsub;
      gload16(&vb[(size_t)(s0 + row) * HIDD + gcol], &Vs[rg * 512]);
    }
    __syncthreads();
    f32x4_t acc[4] = {};
#pragma unroll
    for (int kk = 0; kk < 2; ++kk) {
      int r = w * 16 + fr;  // s-row within chunk
      bf16x8_t af = *(const bf16x8_t*)&Vs[r * 64 + (((kk * 4 + g) ^ (r & 7)) * 8)];
#pragma unroll
      for (int ni = 0; ni < 4; ++ni)
        acc[ni] = __builtin_amdgcn_mfma_f32_16x16x32_bf16(af, bfg[ni][kk], acc[ni], 0, 0, 0);
    }
#pragma unroll
    for (int ni = 0; ni < 4; ++ni)
#pragma unroll
      for (int j = 0; j < 4; ++j)
        ob[(size_t)(s0 + w * 16 + g * 4 + j) * HIDD + ni * 16 + fr] = f2bf(acc[ni][j]);
    __syncthreads();
  }
}

extern "C" void kernel_launch(void* const* d_in, const int* in_sizes, int n_in,
                              void* d_out, int out_size, void* d_ws, size_t ws_size,
                              hipStream_t stream) {
  const float* x = (const float*)d_in[0];
  const float* Wqkv = (const float*)d_in[1];
  const float* bqkv = (const float*)d_in[2];
  const float* Wz = (const float*)d_in[3];
  const float* bz = (const float*)d_in[4];
  const float* temperature = (const float*)d_in[5];

  char* ws = (char*)d_ws;
  ushort* xb   = (ushort*)(ws + 0);           // 33,554,432 (alias: attnout)
  ushort* wqb  = (ushort*)(ws + 33554432);    // 6,291,456
  ushort* wzb  = (ushort*)(ws + 39845888);    // 2,097,152
  ushort* vbuf = (ushort*)(ws + 41943040);    // 33,554,432
  ushort* qkvT = (ushort*)(ws + 75497472);    // 67,108,864  [t][b][h][d][s]
  float* invq  = (float*)(ws + 142606336);    // 16,384
  float* invk  = (float*)(ws + 142622720);    // 16,384
  float* Wpart = (float*)(ws + 142639104);    // 4,194,304
  ushort* attnout = xb;  // x is dead after QKV GEMM

  // 1) converts
  k_f2bf<<<dim3(16384), dim3(256), 0, stream>>>(x, xb, (MM * HIDD) / 4);
  k_f2bf<<<dim3(3072), dim3(256), 0, stream>>>(Wqkv, wqb, (NQKV * HIDD) / 4);
  k_f2bf<<<dim3(1024), dim3(256), 0, stream>>>(Wz, wzb, (HIDD * HIDD) / 4);

  // 2) QKV GEMM -> QT/KT transposed + V natural
  k_gemm8p<2><<<dim3(MM / 256, NQKV / 256), dim3(512), 0, stream>>>(
      xb, wqb, bqkv, nullptr, qkvT, vbuf, MM, NQKV, HIDD);

  // 3) gram partials (MFMA) + norms
  k_gram<<<dim3(64, 4), dim3(256), 0, stream>>>(qkvT, Wpart);
  k_norms<<<dim3(2048), dim3(256), 0, stream>>>(qkvT, invq, invk);

  // 4) fused softmax + PV (MFMA)
  k_pv<<<dim3(64, 4), dim3(256), 0, stream>>>(vbuf, Wpart, invq, invk, temperature,
                                              attnout);

  // 5) output GEMM -> d_out fp32
  k_gemm8p<1><<<dim3(MM / 256, HIDD / 256), dim3(512), 0, stream>>>(
      attnout, wzb, bz, d_out, nullptr, nullptr, MM, HIDD, HIDD);
}